// Round 12
// baseline (75.492 us; speedup 1.0000x reference)
//
#include <hip/hip_runtime.h>

// Problem constants
#define BB 8
#define CIN 16
#define COUT 64
#define HH 32
#define WW 32
// padded plane: 34 rows x 36 cols (cols -1..34; rows -1..32)
#define PH 34
#define PW 36
#define PPLANE (PH * PW) // 1224

// denom = 2*N_EKV*VT = 0.075. Pre-scaled log2-units:
//   xp = x*C, th' = clip(theta,1,8)*C, C = log2(e)/0.075; b1 = xp - th'
//   e2 = e1 * 2^(-0.1*C).  Reference clip(a,-50,20) == post-log
//   l = min(log2(1+2^b), B_HI) (fp32-exact; see earlier rounds).
//   d >= 1.6: both l's hit B_HI -> cancel exactly. d <= -0.72: f < 5e-9 -> skip.
#define SCALE_C 19.235933878519388f /* (1/0.075)*log2(e) */
#define K2E 0.26359713811472845f    /* 2^(-0.1*SCALE_C) = e^(-4/3) */
#define B_HI 28.85390081777927f     /* 20*log2e */
#define WINLO_S (-13.849872392533959f) /* -0.72 * SCALE_C */
#define OUT_CONST (0.4804530139182014f * 0.05625f * 0.1f) /* ln2^2*ALPHA*R */

#define EXP2F(x) __builtin_amdgcn_exp2f(x)
#define LOG2F(x) __builtin_amdgcn_logf(x)

#define NTH (COUT * CIN * 9) // 9216

// blocks 0..611: pad+prescale x into xp ([8][16][34][36]);
// blocks 612..647: prescale clipped theta (9216 elems).
__global__ __launch_bounds__(256) void init_kernel(const float* __restrict__ x,
                                                   const float* __restrict__ theta,
                                                   float* __restrict__ xp,
                                                   float* __restrict__ thp) {
    if (blockIdx.x < 612) {
        int idx = blockIdx.x * 256 + threadIdx.x; // 612*256 = 156672 exactly
        int c = idx / PPLANE;
        int r = idx - c * PPLANE;
        int y = r / PW;
        int xc = r - y * PW;
        float v = 0.0f;
        if (y >= 1 && y <= HH && xc >= 1 && xc <= WW) {
            v = x[c * (HH * WW) + (y - 1) * WW + (xc - 1)] * SCALE_C;
        }
        xp[idx] = v;
    } else {
        int i = (blockIdx.x - 612) * 256 + threadIdx.x;
        if (i < NTH) {
            thp[i] = fminf(fmaxf(theta[i], 1.0f), 8.0f) * SCALE_C;
        }
    }
}

// 3 align-4 dwordx4 rows per cin cover BOTH pixels' 3x3 windows (cols
// owp-1..owp+2 in original coords).
__device__ __forceinline__ void load12(const float* __restrict__ p, float4* v) {
#pragma unroll
    for (int dy = 0; dy < 3; ++dy)
        __builtin_memcpy(&v[dy], p + dy * PW, 16);
}

__device__ __forceinline__ void eval_tap(float b1, float& acc) {
    float e1 = EXP2F(b1);
    float e2 = e1 * K2E;
    float l1 = fminf(LOG2F(1.0f + e1), B_HI);
    float l2 = fminf(LOG2F(1.0f + e2), B_HI);
    acc = fmaf(l1, l1, acc);
    acc = fmaf(-l2, l2, acc);
}

// Per tap: ONE shared window check (max of the 2 pixels) guards TWO
// independent eval chains (ILP-2 inside the taken body). Check is strictly
// more inclusive than per-pixel checks -> accuracy unchanged-or-better.
__device__ __forceinline__ void compute18(const float4* v, const float* __restrict__ thp,
                                          float* acc0, float* acc1) {
#pragma unroll
    for (int dy = 0; dy < 3; ++dy) {
        float c0 = v[dy].x, c1 = v[dy].y, c2 = v[dy].z, c3 = v[dy].w;
        float p0[3] = {c0, c1, c2};
        float p1[3] = {c1, c2, c3};
#pragma unroll
        for (int dx = 0; dx < 3; ++dx) {
            float th = thp[dy * 3 + dx];
            float bm = fmaxf(p0[dx], p1[dx]) - th;
            if (__any(bm > WINLO_S)) {
                eval_tap(p0[dx] - th, acc0[dx]);
                eval_tap(p1[dx] - th, acc1[dx]);
            }
        }
    }
}

// 1024 blocks = b(8) x tile(2) x co(64), XCD-aware decode: b = bid&7 (XCD),
// tile = (bid>>3)&1, co = (bid>>8)*16 + ((bid>>4)&15) -> the 4 co-resident
// blocks per CU share the same (b,tile) x-slice (L1-hot), differ in co-high.
// Each thread: 2 horizontally-adjacent pixels. 4 waves/SIMD x ILP-2.
__global__ __launch_bounds__(256, 4) void ekv_kernel(const float* __restrict__ xp,
                                                     const float* __restrict__ thp,
                                                     const float* __restrict__ scale,
                                                     float* __restrict__ out) {
    int bid = blockIdx.x;
    int b = bid & 7;
    int tile = (bid >> 3) & 1;
    int co = (bid >> 8) * 16 + ((bid >> 4) & 15);

    int t = threadIdx.x;
    int owp = (t & 15) * 2;       // first of the 2 pixels
    int oh = tile * 16 + (t >> 4);

    const float* thc = thp + co * (CIN * 9);
    // Pixel pair (oh, owp..owp+1): taps at padded rows oh..oh+2, cols owp..owp+3.
    const float* p0 = xp + (size_t)b * (CIN * PPLANE) + oh * PW + owp;

    float acc0[3] = {0.0f, 0.0f, 0.0f};
    float acc1[3] = {0.0f, 0.0f, 0.0f};

    // Register ping-pong over cin: prefetch next plane's 3 dwordx4 rows while
    // current plane's 9 shared-check evals run.
    float4 va[3], vb[3];
    load12(p0, va);
#pragma unroll 1
    for (int cin = 0; cin < CIN; cin += 2) {
        load12(p0 + (cin + 1) * PPLANE, vb);
        compute18(va, thc + cin * 9, acc0, acc1);
        int nc = cin + 2 < CIN ? cin + 2 : CIN - 1; // clamp: harmless re-read
        load12(p0 + nc * PPLANE, va);
        compute18(vb, thc + (cin + 1) * 9, acc0, acc1);
    }

    float sc = scale[0] * (OUT_CONST);
    float2 st;
    st.x = (acc0[0] + acc0[1] + acc0[2]) * sc;
    st.y = (acc1[0] + acc1[1] + acc1[2]) * sc;
    float2* op = (float2*)(out + ((((size_t)b * COUT + co) * HH + oh) * WW + owp));
    *op = st;
}

extern "C" void kernel_launch(void* const* d_in, const int* in_sizes, int n_in,
                              void* d_out, int out_size, void* d_ws, size_t ws_size,
                              hipStream_t stream) {
    const float* x = (const float*)d_in[0];
    const float* theta = (const float*)d_in[1];
    const float* scale = (const float*)d_in[2];
    float* out = (float*)d_out;

    // ws layout: [0, 36KB) prescaled theta (9216 f32); then padded x (156672 f32)
    float* thp = (float*)d_ws;
    float* xp = thp + NTH;
    (void)ws_size;

    init_kernel<<<612 + (NTH + 255) / 256, 256, 0, stream>>>(x, theta, xp, thp);
    ekv_kernel<<<BB * 2 * COUT, 256, 0, stream>>>(xp, thp, scale, out);
}